// Round 2
// baseline (248.129 us; speedup 1.0000x reference)
//
#include <hip/hip_runtime.h>

typedef unsigned int u32;
typedef __attribute__((ext_vector_type(2))) float f32x2;

#define JAX_PARTITIONABLE 1

// ---------- Threefry-2x32, 20 rounds (matches jax._src.prng.threefry2x32) ----
__host__ __device__ static inline void tf2x32(u32 k0, u32 k1, u32 x0, u32 x1,
                                              u32* o0, u32* o1)
{
  const u32 ks2 = k0 ^ k1 ^ 0x1BD11BDAu;
#define TF_R(v, r) (((v) << (r)) | ((v) >> (32 - (r))))
#define TF_RND(r) do { x0 += x1; x1 = TF_R(x1, r); x1 ^= x0; } while (0);
  x0 += k0; x1 += k1;
  TF_RND(13) TF_RND(15) TF_RND(26) TF_RND(6)
  x0 += k1;  x1 += ks2 + 1u;
  TF_RND(17) TF_RND(29) TF_RND(16) TF_RND(24)
  x0 += ks2; x1 += k0 + 2u;
  TF_RND(13) TF_RND(15) TF_RND(26) TF_RND(6)
  x0 += k0;  x1 += k1 + 3u;
  TF_RND(17) TF_RND(29) TF_RND(16) TF_RND(24)
  x0 += k1;  x1 += ks2 + 4u;
  TF_RND(13) TF_RND(15) TF_RND(26) TF_RND(6)
  x0 += ks2; x1 += k0 + 5u;
  *o0 = x0; *o1 = x1;
#undef TF_RND
#undef TF_R
}

// ---------- K0: x = q @ W_in (seq-d fma chain), rates, gate probs -----------
// np: x = BLAS sgemm (sequential-k FMA, single accumulator) — replicated.
// np: logits = x @ gk (chain from 0), THEN + bias, THEN / temp.
__global__ __launch_bounds__(64) void k_gate(
    const float* __restrict__ q, const float* __restrict__ win,
    const float* __restrict__ gbias, const float* __restrict__ temp,
    const float* __restrict__ gk, float* __restrict__ rates,
    float* __restrict__ gateo)
{
  const int b = blockIdx.x, j = threadIdx.x;
  __shared__ float xs[64];
  const float* __restrict__ qr = q + b * 1024;   // qr[d] uniform -> s_load
  float c = 0.f;
  for (int d = 0; d < 1024; ++d)
    c = __builtin_fmaf(qr[d], win[d * 64 + j], c);
  const float x = c;
  // stable sigmoid (exp ulps vs np.exp accepted)
  float r;
  if (x >= 0.f) r = __fdiv_rn(1.f, __fadd_rn(1.f, expf(-x)));
  else { const float ex = expf(x); r = __fdiv_rn(ex, __fadd_rn(1.f, ex)); }
  rates[b * 64 + j] = r;
  xs[j] = x;
  __syncthreads();
  if (j < 16) {
    float l = 0.f;
    for (int d = 0; d < 64; ++d)
      l = __builtin_fmaf(xs[d], gk[d * 16 + j], l);
    l = __fadd_rn(l, gbias[j]);
    l = __fdiv_rn(l, temp[0]);
    float m = l;
    for (int off = 1; off < 16; off <<= 1) m = fmaxf(m, __shfl_xor(m, off, 16));
    const float p = expf(__fsub_rn(l, m));
    float s = p;
    for (int off = 1; off < 16; off <<= 1) s += __shfl_xor(s, off, 16);
    gateo[b * 16 + j] = __fdiv_rn(p, s);
  }
}

// ---------- K1: Poisson spikes via threefry -> f32 0/1, layout [T][B][D] -----
__global__ __launch_bounds__(256) void k_spikes(
    const float* __restrict__ rates, float* __restrict__ spkf, u32 bk0, u32 bk1)
{
  const u32 g = blockIdx.x * 256u + threadIdx.x;
#if JAX_PARTITIONABLE
  u32 o0, o1;
  tf2x32(bk0, bk1, 0u, g, &o0, &o1);            // 64-bit counter (0, g)
  const u32 bits = o0 ^ o1;
  const float r = rates[g & 16383u];
  const float u = __uint_as_float((bits >> 9) | 0x3f800000u) - 1.0f;
  spkf[g] = (u < r) ? 1.0f : 0.0f;
#else
  u32 o0, o1;
  tf2x32(bk0, bk1, g, g + 163840u, &o0, &o1);
  const float r = rates[g & 16383u];
  const float ua = __uint_as_float((o0 >> 9) | 0x3f800000u) - 1.0f;
  const float ub = __uint_as_float((o1 >> 9) | 0x3f800000u) - 1.0f;
  spkf[g] = (ua < r) ? 1.0f : 0.0f;
  spkf[g + 163840u] = (ub < r) ? 1.0f : 0.0f;
#endif
}

// ---------- K2: bit-exact LIF scan ------------------------------------------
// thread <-> (e, h-pair); W[e,:,h] in 128 VGPRs (static idx only);
// current = ascending-d fp32 fma chain (spike 0/1 exact, fma(0,w,c)=c);
// v-update = np op order with contraction blocked (__f*_rn).
// grid (2 h-chunks, 32 b-chunks, 16 e), 256 thr.
__global__ __launch_bounds__(256) void k_lif(
    const float* __restrict__ spkf, const float* __restrict__ w,
    float* __restrict__ avg)
{
  const int e = blockIdx.z;
  const int hp = blockIdx.x * 256 + threadIdx.x;   // [0,512)
  const int h0 = hp * 2;
  f32x2 w2[64];
  const float* __restrict__ wb = w + (size_t)e * 65536 + h0;
#pragma unroll
  for (int d = 0; d < 64; ++d)
    w2[d] = *(const f32x2*)(wb + d * 1024);

  const int b0 = blockIdx.y * 8;
  for (int bb = 0; bb < 8; ++bb) {
    const int b = b0 + bb;
    float vx = 0.f, vy = 0.f, cnx = 0.f, cny = 0.f;
    for (int t = 0; t < 20; ++t) {
      const float* __restrict__ srow = spkf + (size_t)(t * 256 + b) * 64;
      float cx = 0.f, cy = 0.f;
#pragma unroll
      for (int d = 0; d < 64; ++d) {
        const float sv = srow[d];                  // wave-uniform -> s_load
        cx = __builtin_fmaf(sv, w2[d].x, cx);
        cy = __builtin_fmaf(sv, w2[d].y, cy);
      }
      // np: t1 = current - v; t2 = t1 * leak; new_v = v + t2  (3 roundings)
      const float d1x = __fsub_rn(cx, vx), d1y = __fsub_rn(cy, vy);
      const float d2x = __fmul_rn(d1x, 0.05f), d2y = __fmul_rn(d1y, 0.05f);
      const float nvx = __fadd_rn(vx, d2x), nvy = __fadd_rn(vy, d2y);
      if (nvx >= 0.5f) { cnx += 1.f; vx = 0.f; } else vx = nvx;
      if (nvy >= 0.5f) { cny += 1.f; vy = 0.f; } else vy = nvy;
    }
    f32x2 av;
    av.x = __fdiv_rn(cnx, 20.f);                   // np mean: sum/20, true div
    av.y = __fdiv_rn(cny, 20.f);
    *(f32x2*)(avg + ((size_t)e * 256 + b) * 1024 + h0) = av;
  }
}

// ---------- K3: out[b,h] = ascending-e fma chain of avg*p -------------------
__global__ __launch_bounds__(256) void k_combine(
    const float* __restrict__ avg, const float* __restrict__ gateo,
    float* __restrict__ out)
{
  const int idx = blockIdx.x * 256 + threadIdx.x;
  const int b = idx >> 10, h = idx & 1023;
  float s = 0.f;
#pragma unroll
  for (int e = 0; e < 16; ++e)
    s = __builtin_fmaf(avg[((size_t)e * 256 + b) * 1024 + h],
                       gateo[b * 16 + e], s);
  out[idx] = s;
}

// ---------- launch ----------------------------------------------------------
extern "C" void kernel_launch(void* const* d_in, const int* in_sizes, int n_in,
                              void* d_out, int out_size, void* d_ws, size_t ws_size,
                              hipStream_t stream)
{
  (void)in_sizes; (void)n_in; (void)out_size; (void)ws_size;
  const float* q     = (const float*)d_in[0];
  const float* gbias = (const float*)d_in[1];
  const float* temp  = (const float*)d_in[2];
  const float* win   = (const float*)d_in[3];
  const float* ex    = (const float*)d_in[4];
  const float* gk    = (const float*)d_in[5];
  float* out = (float*)d_out;

  char* ws = (char*)d_ws;
  float* spkf  = (float*)(ws + 0);          // [20][256][64] f32   1310720 B
  float* rates = (float*)(ws + 1310720);    // [256][64] f32         65536 B
  float* gateo = (float*)(ws + 1376256);    // [256][16] f32         16384 B
  float* avg   = (float*)(ws + 1392640);    // [16][256][1024] f32 16777216 B
                                            // total: 18169856 B

  // bern_key = jax.random.split(jax.random.key(0))[1], computed on host
  u32 bk0, bk1;
#if JAX_PARTITIONABLE
  tf2x32(0u, 0u, 0u, 1u, &bk0, &bk1);
#else
  u32 a0o, a1o, b0o, b1o;
  tf2x32(0u, 0u, 0u, 2u, &a0o, &a1o);
  tf2x32(0u, 0u, 1u, 3u, &b0o, &b1o);
  bk0 = a1o; bk1 = b1o;
#endif

  k_gate<<<256, 64, 0, stream>>>(q, win, gbias, temp, gk, rates, gateo);
#if JAX_PARTITIONABLE
  k_spikes<<<1280, 256, 0, stream>>>(rates, spkf, bk0, bk1);
#else
  k_spikes<<<640, 256, 0, stream>>>(rates, spkf, bk0, bk1);
#endif
  k_lif<<<dim3(2, 32, 16), 256, 0, stream>>>(spkf, ex, avg);
  k_combine<<<1024, 256, 0, stream>>>(avg, gateo, out);
}